// Round 1
// baseline (176.430 us; speedup 1.0000x reference)
//
#include <hip/hip_runtime.h>
#include <hip/hip_bf16.h>

#define NB 256
#define IN_F 16
#define HID 64
#define GDIM 64
#define NGP 4
#define PW 68   // xcb row stride (floats); 68*4B = 272B, 16B-aligned rows

// ---------------- compile-time algebra tables ----------------
namespace alg {
constexpr int popc(int x){int c=0;while(x){c+=x&1;x>>=1;}return c;}
struct Tables {
  int qt[64];                 // orig index -> grade%4
  int perm[64];               // slot -> orig index (class-grouped)
  int inv[64];                // orig -> slot
  unsigned char kslot[64][64];// [j_slot][i_slot] -> k_slot
  unsigned char widx [64][64];// [j_slot][i_slot] -> qt_i*16+qt_j*4+qt_k
  unsigned char sgn  [64][64];// 1 = negative
};
constexpr Tables build(){
  Tables t{};
  int mask[64]={}; int pos[64]={};
  int idx=0;
  for(int pc=0;pc<=6;++pc) for(int m=0;m<64;++m) if(popc(m)==pc) mask[idx++]=m;
  for(int i=0;i<64;++i) pos[mask[i]]=i;
  for(int i=0;i<64;++i) t.qt[i]=popc(mask[i])&3;
  int s=0;
  for(int c=0;c<4;++c) for(int i=0;i<64;++i) if(t.qt[i]==c){t.perm[s]=i;t.inv[i]=s;++s;}
  for(int js=0;js<64;++js) for(int is=0;is<64;++is){
    int oi=t.perm[is], oj=t.perm[js];
    int mk=mask[oi]^mask[oj];
    int ok=pos[mk];
    t.kslot[js][is]=(unsigned char)t.inv[ok];
    t.widx [js][is]=(unsigned char)(t.qt[oi]*16+t.qt[oj]*4+t.qt[ok]);
    int scnt=0, tt=mask[oi]>>1;
    while(tt){scnt+=popc(tt&mk);tt>>=1;}
    t.sgn[js][is]=(unsigned char)(scnt&1);
  }
  return t;
}
constexpr Tables T = build();
// class-contiguous slot ranges: sizes 16,12,16,20
constexpr int CLS_BEG[4] = {0,16,28,44};
constexpr int CLS_END[4] = {16,28,44,64};
}

// ---------------- prep: transpose weights into workspace ----------------
// lw_t[((l*4+c)*64+m)*64+f] = gp_lin_w[((l*64+f)*64+m)*4+c]   (65536 floats)
// gpw_t[(l*64+k)*64+f]      = gp_w[(l*64+f)*64+k]             (16384 floats)
__global__ void ga_prep(const float* __restrict__ gp_lin_w,
                        const float* __restrict__ gp_w,
                        float* __restrict__ lw_t, float* __restrict__ gpw_t,
                        float* __restrict__ out) {
  const int bx = blockIdx.x, t = threadIdx.x;
  if (bx == 0 && t == 0) out[0] = 0.f;   // mean accumulator init
  if (bx < 256) {
    int o = bx*256 + t;
    int f = o & 63, m = (o>>6)&63, c = (o>>12)&3, l = (o>>14)&3;
    lw_t[o] = gp_lin_w[((l*64+f)*64+m)*4 + c];
  } else {
    int o = (bx-256)*256 + t;
    int f = o & 63, k = (o>>6)&63, l = (o>>12)&3;
    gpw_t[o] = gp_w[(l*64+f)*64 + k];
  }
}

// ---------------- qt-linear body: 16 output blades, split between 2 classes ----
template<int SPLIT>
__device__ __forceinline__ void lin_body(const float* __restrict__ xcb,
    const float* __restrict__ lwA, const float* __restrict__ lwB,
    int colbase, float (&acc)[16]) {
  #pragma unroll 8
  for (int m = 0; m < 64; ++m) {
    const float4 x0 = *(const float4*)(xcb + m*PW + colbase + 0);
    const float4 x1 = *(const float4*)(xcb + m*PW + colbase + 4);
    const float4 x2 = *(const float4*)(xcb + m*PW + colbase + 8);
    const float4 x3 = *(const float4*)(xcb + m*PW + colbase + 12);
    const float wa = lwA[m*64];
    const float wb = lwB[m*64];
    const float xv[16] = {x0.x,x0.y,x0.z,x0.w, x1.x,x1.y,x1.z,x1.w,
                          x2.x,x2.y,x2.z,x2.w, x3.x,x3.y,x3.z,x3.w};
    #pragma unroll
    for (int ii = 0; ii < 16; ++ii)
      acc[ii] = fmaf((ii < SPLIT) ? wa : wb, xv[ii], acc[ii]);
  }
}

// ---------------- geometric-product body: fully unrolled vs constexpr tables ----
template<int JC>
__device__ __forceinline__ void gp_body(const float* __restrict__ xbcf,
    const float (&yreg)[64], const float (&wreg)[64], float (&acc)[16]) {
  #pragma unroll
  for (int is = 0; is < 64; ++is) {
    const float xi = xbcf[is*64];
    #pragma unroll
    for (int jj = 0; jj < 16; ++jj) {
      const int js = JC*16 + jj;
      const int k  = alg::T.kslot[js][is];
      const int w  = alg::T.widx [js][is];
      const float tp = wreg[w] * yreg[k];
      acc[jj] = alg::T.sgn[js][is] ? fmaf(-tp, xi, acc[jj])
                                   : fmaf( tp, xi, acc[jj]);
    }
  }
}

// ---------------- main fused kernel: one block per batch element ----------------
__global__ __launch_bounds__(256, 1) void ga_main(
    const float* __restrict__ points, const float* __restrict__ products,
    const float* __restrict__ lin_w,  const float* __restrict__ lin_b,
    const float* __restrict__ gp_a,
    const float* __restrict__ mlp_w1, const float* __restrict__ mlp_b1,
    const float* __restrict__ mlp_w2, const float* __restrict__ mlp_b2,
    const float* __restrict__ lw_t,   const float* __restrict__ gpw_t,
    float* __restrict__ d_out)
{
  __shared__ __align__(16) float xcb[64*PW];   // [channel][blade-slot], pad 68
  __shared__ float xbc[64*64];                 // [blade-slot][channel]
  __shared__ float ybc[64*64];                 // [blade-slot][channel]
  __shared__ float invn[4*64];                 // [class][channel]
  __shared__ float red[4*64];
  __shared__ float pts[96];
  __shared__ float ynrm[64];

  const int t  = threadIdx.x;
  const int b  = blockIdx.x;
  const int f  = t & 63;
  const int jc = t >> 6;

  // zero multivector state
  for (int i = t; i < 64*PW; i += 256) xcb[i] = 0.f;
  for (int i = t; i < 64*64; i += 256) xbc[i] = 0.f;
  if (t < 96) pts[t] = points[b*96 + t];
  __syncthreads();

  // phase 0: embed grade-1 + first qt-linear (only scalar + 6 grade-1 slots nonzero)
  if (t < 64) {
    float a[6] = {0,0,0,0,0,0};
    for (int m = 0; m < IN_F; ++m) {
      float lw = lin_w[(t*IN_F+m)*4 + 1];   // qt(grade1)=1
      #pragma unroll
      for (int g = 0; g < 6; ++g) a[g] = fmaf(pts[m*6+g], lw, a[g]);
    }
    float bias = lin_b[t];
    xcb[t*PW + 0] = bias; xbc[0*64 + t] = bias;   // scalar blade -> slot 0
    #pragma unroll
    for (int g = 0; g < 6; ++g) {                  // grade1 -> slots 16..21 (class1 head)
      xcb[t*PW + 16+g] = a[g];
      xbc[(16+g)*64 + t] = a[g];
    }
  }
  __syncthreads();

  float gacc[16];   // GP output of current layer (final layer's stays here)

  for (int l = 0; l < NGP; ++l) {
    // ---- qt-linear (reads xcb, coalesced lw_t from global) ----
    float lacc[16];
    #pragma unroll
    for (int ii=0;ii<16;++ii) lacc[ii]=0.f;
    {
      const int colbase = jc*16;
      const float* base = lw_t + l*16384 + f;
      if      (jc==0) lin_body<16>(xcb, base + 0*4096, base + 0*4096, colbase, lacc);
      else if (jc==1) lin_body<12>(xcb, base + 1*4096, base + 2*4096, colbase, lacc);
      else if (jc==2) lin_body<12>(xcb, base + 2*4096, base + 3*4096, colbase, lacc);
      else            lin_body<16>(xcb, base + 3*4096, base + 3*4096, colbase, lacc);
    }
    #pragma unroll
    for (int ii=0;ii<16;++ii) ybc[(jc*16+ii)*64 + f] = lacc[ii];
    __syncthreads();

    // ---- per-(channel,class) norms -> folded inverse scales ----
    {
      const int c = jc;
      float s = 0.f;
      for (int i = alg::CLS_BEG[c]; i < alg::CLS_END[c]; ++i) {
        float v = ybc[i*64+f]; s = fmaf(v,v,s);
      }
      s = fmaxf(s, 1e-12f);
      float nrm = sqrtf(s);
      float av  = gp_a[(l*64+f)*4 + c];
      float sig = 1.f/(1.f + expf(-av));
      float nn  = sig*(nrm-1.f) + 1.f;
      invn[c*64+f] = 1.f/(nn + 1e-6f);
    }
    __syncthreads();

    // ---- geometric product ----
    float yreg[64], wreg[64];
    #pragma unroll
    for (int k=0;k<64;++k) yreg[k] = ybc[k*64+f];
    {
      const float in0 = invn[0*64+f], in1 = invn[1*64+f],
                  in2 = invn[2*64+f], in3 = invn[3*64+f];
      const float* wrow = gpw_t + l*4096 + f;   // [widx][f], coalesced
      #pragma unroll
      for (int k=0;k<64;++k) {
        const float sc = ((k&3)==0)?in0:(((k&3)==1)?in1:(((k&3)==2)?in2:in3));
        wreg[k] = wrow[k*64] * sc;
      }
    }
    #pragma unroll
    for (int ii=0;ii<16;++ii) gacc[ii]=0.f;
    {
      const float* xbcf = xbc + f;
      if      (jc==0) gp_body<0>(xbcf, yreg, wreg, gacc);
      else if (jc==1) gp_body<1>(xbcf, yreg, wreg, gacc);
      else if (jc==2) gp_body<2>(xbcf, yreg, wreg, gacc);
      else            gp_body<3>(xbcf, yreg, wreg, gacc);
    }
    __syncthreads();           // all xbc reads done before overwrite
    if (l < NGP-1) {
      #pragma unroll
      for (int ii=0;ii<16;++ii) {
        const int s = jc*16+ii;
        xcb[f*PW + s]  = gacc[ii];
        xbc[s*64 + f]  = gacc[ii];
      }
      __syncthreads();
    }
  }

  // ---- tail: blade-norm -> MLP -> loss ----
  float ss = 0.f;
  #pragma unroll
  for (int ii=0;ii<16;++ii) ss = fmaf(gacc[ii],gacc[ii],ss);
  red[jc*64+f] = ss;
  __syncthreads();
  if (t < 64) ynrm[t] = sqrtf(red[t] + red[64+t] + red[128+t] + red[192+t]);
  __syncthreads();
  {
    float hp = 0.f;
    for (int f2 = jc*16; f2 < jc*16+16; ++f2)
      hp = fmaf(mlp_w1[f*64+f2], ynrm[f2], hp);
    red[jc*64+f] = hp;
  }
  __syncthreads();
  if (t < 64) {
    float hpre = mlp_b1[t] + red[t] + red[64+t] + red[128+t] + red[192+t];
    float h = hpre / (1.f + expf(-hpre));   // silu
    float p = h * mlp_w2[t];
    #pragma unroll
    for (int off = 32; off > 0; off >>= 1) p += __shfl_down(p, off, 64);
    if (t == 0) {
      float pred = p + mlp_b2[0];
      float d = pred - products[b];
      float loss = d*d;
      d_out[1+b] = loss;
      atomicAdd(d_out, loss * (1.f/256.f));
    }
  }
}

extern "C" void kernel_launch(void* const* d_in, const int* in_sizes, int n_in,
                              void* d_out, int out_size, void* d_ws, size_t ws_size,
                              hipStream_t stream) {
  const float* points   = (const float*)d_in[0];
  const float* products = (const float*)d_in[1];
  const float* lin_w    = (const float*)d_in[2];
  const float* lin_b    = (const float*)d_in[3];
  const float* gp_lin_w = (const float*)d_in[4];
  const float* gp_a     = (const float*)d_in[5];
  const float* gp_w     = (const float*)d_in[6];
  const float* mlp_w1   = (const float*)d_in[7];
  const float* mlp_b1   = (const float*)d_in[8];
  const float* mlp_w2   = (const float*)d_in[9];
  const float* mlp_b2   = (const float*)d_in[10];
  float* out = (float*)d_out;

  float* lw_t  = (float*)d_ws;        // 65536 floats = 256 KB
  float* gpw_t = lw_t + 65536;        // 16384 floats =  64 KB

  ga_prep<<<320, 256, 0, stream>>>(gp_lin_w, gp_w, lw_t, gpw_t, out);
  ga_main<<<NB, 256, 0, stream>>>(points, products, lin_w, lin_b, gp_a,
                                  mlp_w1, mlp_b1, mlp_w2, mlp_b2,
                                  lw_t, gpw_t, out);
}